// Round 2
// baseline (5578.862 us; speedup 1.0000x reference)
//
#include <hip/hip_runtime.h>
#include <math.h>

#define HD 64

__device__ __forceinline__ float sigf(float x) {
    return __builtin_amdgcn_rcpf(1.0f + __expf(-x));
}
__device__ __forceinline__ float tanh_fast(float x) {
    float ax = fabsf(x);
    float e  = __expf(-2.0f * ax);
    return copysignf((1.0f - e) * __builtin_amdgcn_rcpf(1.0f + e), x);
}

// 32-wide partial dot: w[8] (float4 half-row) . hv[8] (LDS half of h, broadcast)
__device__ __forceinline__ float dot32(const float4* w, const float4* hv) {
    float4 a = make_float4(0.f, 0.f, 0.f, 0.f);
#pragma unroll
    for (int q = 0; q < 8; q++) {
        float4 h = hv[q];
        a.x += w[q].x * h.x; a.y += w[q].y * h.y;
        a.z += w[q].z * h.z; a.w += w[q].w * h.w;
    }
    return (a.x + a.y) + (a.z + a.w);
}

// One block per batch element. 512 threads: gate row r = tid&255, half = tid>>8.
// Each thread holds 32-element half-rows of the recurrent weights in registers.
__global__ __launch_bounds__(512, 4)
void seq2seq_kernel(const float* __restrict__ src, const float* __restrict__ trg,
                    const float* __restrict__ e1ih, const float* __restrict__ e1hh,
                    const float* __restrict__ e1b,
                    const float* __restrict__ e2ih, const float* __restrict__ e2hh,
                    const float* __restrict__ e2b,
                    const float* __restrict__ d1ih, const float* __restrict__ d1hh,
                    const float* __restrict__ d1b,
                    const float* __restrict__ d2ih, const float* __restrict__ d2hh,
                    const float* __restrict__ d2b,
                    const float* __restrict__ fcW, const float* __restrict__ fcb,
                    float* __restrict__ out)
{
    const int b    = blockIdx.x;
    const int tid  = threadIdx.x;
    const int r    = tid & 255;
    const int half = tid >> 8;
    const int u    = tid & 63;

    __shared__ float sx[3072];                 // src[b]: 1024*3
    __shared__ float tx[1536];                 // trg[b]: 512*3
    __shared__ float part[512];                // [half][row] partial gate sums
    __shared__ __align__(16) float h1[HD];
    __shared__ __align__(16) float h2[HD];

    // stage inputs (coalesced)
    {
        const float* srow = src + (size_t)b * 3072;
        for (int i = tid; i < 3072; i += 512) sx[i] = srow[i];
        const float* trow = trg + (size_t)b * 1536;
        for (int i = tid; i < 1536; i += 512) tx[i] = trow[i];
    }

    // ---------------- encoder weights (register-resident half-rows) --------
    float4 wh1[8], wi2[8], wh2[8];
    {
        const float4* p1 = (const float4*)(e1hh + (size_t)r * 64) + half * 8;
        const float4* p2 = (const float4*)(e2ih + (size_t)r * 64) + half * 8;
        const float4* p3 = (const float4*)(e2hh + (size_t)r * 64) + half * 8;
#pragma unroll
        for (int q = 0; q < 8; q++) { wh1[q] = p1[q]; wi2[q] = p2[q]; wh2[q] = p3[q]; }
    }
    float wi10 = e1ih[r * 3 + 0], wi11 = e1ih[r * 3 + 1], wi12 = e1ih[r * 3 + 2];
    float bb1 = e1b[r], bb2 = e2b[r];

    float c1 = 0.0f, c2 = 0.0f;                // state lives in threads tid<64
    if (tid < HD) { h1[tid] = 0.0f; h2[tid] = 0.0f; }
    __syncthreads();

    const float4* h1v = (const float4*)h1 + half * 8;
    const float4* h2v = (const float4*)h2 + half * 8;

    // ---------------- encoder: 1024 steps, 2 stacked LSTM layers -----------
#pragma unroll 1
    for (int t = 0; t < 1024; t++) {
        // layer-1 half-dot
        float s = dot32(wh1, h1v);
        if (half == 0)
            s += wi10 * sx[t * 3] + wi11 * sx[t * 3 + 1] + wi12 * sx[t * 3 + 2] + bb1;
        part[tid] = s;
        __syncthreads();

        if (tid < HD) {
            float vi = part[u]       + part[256 + u];
            float vf = part[64 + u]  + part[320 + u];
            float vg = part[128 + u] + part[384 + u];
            float vo = part[192 + u] + part[448 + u];
            c1 = sigf(vf) * c1 + sigf(vi) * tanh_fast(vg);
            h1[u] = sigf(vo) * tanh_fast(c1);
        }
        __syncthreads();

        // layer-2 half-dot
        float s2 = dot32(wi2, h1v) + dot32(wh2, h2v);
        if (half == 0) s2 += bb2;
        part[tid] = s2;
        __syncthreads();

        if (tid < HD) {
            float vi = part[u]       + part[256 + u];
            float vf = part[64 + u]  + part[320 + u];
            float vg = part[128 + u] + part[384 + u];
            float vo = part[192 + u] + part[448 + u];
            c2 = sigf(vf) * c2 + sigf(vi) * tanh_fast(vg);
            h2[u] = sigf(vo) * tanh_fast(c2);
        }
        __syncthreads();
    }

    // ---------------- decoder weights (loaded after encoder loop) ----------
    float4 dh1[8], dw2[8];
    {
        const float4* p1 = (const float4*)(d1hh + (size_t)r * 64) + half * 8;
        const float4* pa = (const float4*)(d2ih + (size_t)r * 64) + half * 8;
        const float4* pb = (const float4*)(d2hh + (size_t)r * 64) + half * 8;
#pragma unroll
        for (int q = 0; q < 8; q++) {
            dh1[q] = p1[q];
            float4 x = pa[q], y = pb[q];
            dw2[q] = make_float4(x.x + y.x, x.y + y.y, x.z + y.z, x.w + y.w);
        }
    }
    float di0 = d1ih[r * 3 + 0], di1 = d1ih[r * 3 + 1], di2 = d1ih[r * 3 + 2];
    float db1 = d1b[r], db2 = d2b[r];

    float fw0 = 0.f, fw1 = 0.f, fw2 = 0.f;
    float fb0 = fcb[0], fb1 = fcb[1], fb2 = fcb[2];
    if (tid < HD) { fw0 = fcW[u]; fw1 = fcW[64 + u]; fw2 = fcW[128 + u]; }

    // decoder carry: h = h2 (already in LDS), c = c2 (already in regs, tid<64)
    float cd = c2;

    // ---------------- decoder: 511 steps, 2 chained cells + FC head --------
#pragma unroll 1
    for (int t = 0; t < 511; t++) {
        // dec1 half-dot (reads carry h in h2[])
        float s = dot32(dh1, h2v);
        if (half == 0)
            s += di0 * tx[t * 3] + di1 * tx[t * 3 + 1] + di2 * tx[t * 3 + 2] + db1;
        part[tid] = s;
        __syncthreads();

        float c1d = 0.0f;
        if (tid < HD) {
            float vi = part[u]       + part[256 + u];
            float vf = part[64 + u]  + part[320 + u];
            float vg = part[128 + u] + part[384 + u];
            float vo = part[192 + u] + part[448 + u];
            c1d = sigf(vf) * cd + sigf(vi) * tanh_fast(vg);
            h1[u] = sigf(vo) * tanh_fast(c1d);
        }
        __syncthreads();

        // dec2: x = h = h1 -> (Wih2+Whh2) summed half-dot
        float s2 = dot32(dw2, h1v);
        if (half == 0) s2 += db2;
        part[tid] = s2;
        __syncthreads();

        if (tid < HD) {
            float vi = part[u]       + part[256 + u];
            float vf = part[64 + u]  + part[320 + u];
            float vg = part[128 + u] + part[384 + u];
            float vo = part[192 + u] + part[448 + u];
            float c2d = sigf(vf) * c1d + sigf(vi) * tanh_fast(vg);
            float hh  = sigf(vo) * tanh_fast(c2d);
            cd = c2d;
            h2[u] = hh;
            // FC head: wave-0 shuffle reduction
            float p0 = fw0 * hh, p1 = fw1 * hh, p2 = fw2 * hh;
#pragma unroll
            for (int off = 32; off > 0; off >>= 1) {
                p0 += __shfl_down(p0, off);
                p1 += __shfl_down(p1, off);
                p2 += __shfl_down(p2, off);
            }
            if (u == 0) {
                float* o = out + ((size_t)b * 512 + t + 1) * 3;
                o[0] = p0 + fb0; o[1] = p1 + fb1; o[2] = p2 + fb2;
            }
        }
        __syncthreads();
    }
}

extern "C" void kernel_launch(void* const* d_in, const int* in_sizes, int n_in,
                              void* d_out, int out_size, void* d_ws, size_t ws_size,
                              hipStream_t stream)
{
    const float* src   = (const float*)d_in[0];
    const float* trg   = (const float*)d_in[1];
    const float* e1ih  = (const float*)d_in[2];
    const float* e1hh  = (const float*)d_in[3];
    const float* e1b   = (const float*)d_in[4];
    const float* e2ih  = (const float*)d_in[5];
    const float* e2hh  = (const float*)d_in[6];
    const float* e2b   = (const float*)d_in[7];
    const float* dd1ih = (const float*)d_in[8];
    const float* dd1hh = (const float*)d_in[9];
    const float* dd1b  = (const float*)d_in[10];
    const float* dd2ih = (const float*)d_in[11];
    const float* dd2hh = (const float*)d_in[12];
    const float* dd2b  = (const float*)d_in[13];
    const float* fcW   = (const float*)d_in[14];
    const float* fcb   = (const float*)d_in[15];
    float* out = (float*)d_out;

    // outputs[:, 0, :] stays 0; decoder fills t >= 1
    hipMemsetAsync(d_out, 0, (size_t)out_size * sizeof(float), stream);

    seq2seq_kernel<<<512, 512, 0, stream>>>(src, trg,
                                            e1ih, e1hh, e1b, e2ih, e2hh, e2b,
                                            dd1ih, dd1hh, dd1b, dd2ih, dd2hh, dd2b,
                                            fcW, fcb, out);
}

// Round 3
// 2678.855 us; speedup vs baseline: 2.0826x; 2.0826x over previous
//
#include <hip/hip_runtime.h>
#include <math.h>

#define HD 64

__device__ __forceinline__ float sigf(float x) {
    return __builtin_amdgcn_rcpf(1.0f + __expf(-x));
}
__device__ __forceinline__ float tanh_fast(float x) {
    float ax = fabsf(x);
    float e  = __expf(-2.0f * ax);
    return copysignf((1.0f - e) * __builtin_amdgcn_rcpf(1.0f + e), x);
}
// broadcast lane u's value to all lanes via v_readlane (SGPR, no LDS traffic)
__device__ __forceinline__ float bcast(float v, int u) {
    return __int_as_float(__builtin_amdgcn_readlane(__float_as_int(v), u));
}

// 64-dot: per-thread register weight row w[64] . h, where lane u of THIS wave
// holds h[u] in hreg (state replicated per wave). 4-way split accumulators.
__device__ __forceinline__ float dot64(const float* w, float hreg) {
    float a0 = 0.f, a1 = 0.f, a2 = 0.f, a3 = 0.f;
#pragma unroll
    for (int u = 0; u < 64; u += 4) {
        a0 += w[u + 0] * bcast(hreg, u + 0);
        a1 += w[u + 1] * bcast(hreg, u + 1);
        a2 += w[u + 2] * bcast(hreg, u + 2);
        a3 += w[u + 3] * bcast(hreg, u + 3);
    }
    return (a0 + a1) + (a2 + a3);
}

__device__ __forceinline__ void load_row(float* dst, const float* src) {
    const float4* p = (const float4*)src;
#pragma unroll
    for (int q = 0; q < 16; q++) {
        float4 v = p[q];
        dst[4 * q + 0] = v.x; dst[4 * q + 1] = v.y;
        dst[4 * q + 2] = v.z; dst[4 * q + 3] = v.w;
    }
}

// One block per batch element. 256 threads; thread r owns gate-row r.
// LSTM state (c, h) is REPLICATED per wave: lane u holds h[u]/c[u] in regs.
// Only the 256 activated gate values cross waves through LDS (2 barriers/step).
__global__ __launch_bounds__(256, 2)
void seq2seq_kernel(const float* __restrict__ src, const float* __restrict__ trg,
                    const float* __restrict__ e1ih, const float* __restrict__ e1hh,
                    const float* __restrict__ e1b,
                    const float* __restrict__ e2ih, const float* __restrict__ e2hh,
                    const float* __restrict__ e2b,
                    const float* __restrict__ d1ih, const float* __restrict__ d1hh,
                    const float* __restrict__ d1b,
                    const float* __restrict__ d2ih, const float* __restrict__ d2hh,
                    const float* __restrict__ d2b,
                    const float* __restrict__ fcW, const float* __restrict__ fcb,
                    float* __restrict__ out)
{
    const int b    = blockIdx.x;
    const int r    = threadIdx.x;      // gate row 0..255
    const int lane = r & 63;           // h/c index this lane replicates

    __shared__ float sx[3072];         // src[b]: 1024*3
    __shared__ float tx[1536];         // trg[b]: 512*3
    __shared__ float ga[256];          // layer-1 activated gates
    __shared__ float gb[256];          // layer-2 activated gates

    // stage inputs (coalesced)
    {
        const float* srow = src + (size_t)b * 3072;
        for (int i = r; i < 3072; i += 256) sx[i] = srow[i];
        const float* trow = trg + (size_t)b * 1536;
        for (int i = r; i < 1536; i += 256) tx[i] = trow[i];
    }

    const bool is_g = ((r >> 6) == 2); // rows 128..191 -> tanh gate

    // ---------------- encoder weights: register-resident rows --------------
    float wh1[64], wi2[64], wh2[64];
    load_row(wh1, e1hh + (size_t)r * 64);
    load_row(wi2, e2ih + (size_t)r * 64);
    load_row(wh2, e2hh + (size_t)r * 64);
    float wi10 = e1ih[r * 3 + 0], wi11 = e1ih[r * 3 + 1], wi12 = e1ih[r * 3 + 2];
    float bb1 = e1b[r], bb2 = e2b[r];

    float hr1 = 0.f, hr2 = 0.f, c1 = 0.f, c2 = 0.f;  // replicated state
    __syncthreads();

    // ---------------- encoder: 1024 steps --------------------------------
#pragma unroll 1
    for (int t = 0; t < 1024; t++) {
        // layer-1 gates
        float g = dot64(wh1, hr1)
                + wi10 * sx[t * 3] + wi11 * sx[t * 3 + 1] + wi12 * sx[t * 3 + 2] + bb1;
        ga[r] = is_g ? tanh_fast(g) : sigf(g);
        __syncthreads();

        // layer-1 cell update (redundant in every wave; lane u owns h[u])
        {
            float iv = ga[lane], fv = ga[64 + lane], gv = ga[128 + lane], ov = ga[192 + lane];
            c1 = fv * c1 + iv * gv;
            hr1 = ov * tanh_fast(c1);
        }

        // layer-2 gates (uses NEW h1, OLD h2)
        float g2 = dot64(wi2, hr1) + dot64(wh2, hr2) + bb2;
        gb[r] = is_g ? tanh_fast(g2) : sigf(g2);
        __syncthreads();

        // layer-2 cell update
        {
            float iv = gb[lane], fv = gb[64 + lane], gv = gb[128 + lane], ov = gb[192 + lane];
            c2 = fv * c2 + iv * gv;
            hr2 = ov * tanh_fast(c2);
        }
    }

    // ---------------- decoder weights (reuse dead encoder registers) ------
    float dh1[64], dw2[64];
    load_row(dh1, d1hh + (size_t)r * 64);
    {
        const float4* pa = (const float4*)(d2ih + (size_t)r * 64);
        const float4* pb = (const float4*)(d2hh + (size_t)r * 64);
#pragma unroll
        for (int q = 0; q < 16; q++) {
            float4 x = pa[q], y = pb[q];
            dw2[4 * q + 0] = x.x + y.x; dw2[4 * q + 1] = x.y + y.y;
            dw2[4 * q + 2] = x.z + y.z; dw2[4 * q + 3] = x.w + y.w;
        }
    }
    float di0 = d1ih[r * 3 + 0], di1 = d1ih[r * 3 + 1], di2 = d1ih[r * 3 + 2];
    float db1 = d1b[r], db2 = d2b[r];
    float fw0 = fcW[lane], fw1 = fcW[64 + lane], fw2 = fcW[128 + lane];
    float fb0 = fcb[0], fb1 = fcb[1], fb2 = fcb[2];

    // decoder carry: h = hr2, c = c2 (both replicated per wave)
    float cd = c2;

    // ---------------- decoder: 511 steps ----------------------------------
#pragma unroll 1
    for (int t = 0; t < 511; t++) {
        // dec1 gates
        float g = dot64(dh1, hr2)
                + di0 * tx[t * 3] + di1 * tx[t * 3 + 1] + di2 * tx[t * 3 + 2] + db1;
        ga[r] = is_g ? tanh_fast(g) : sigf(g);
        __syncthreads();

        // dec1 update (redundant)
        float c1d;
        float h1d;
        {
            float iv = ga[lane], fv = ga[64 + lane], gv = ga[128 + lane], ov = ga[192 + lane];
            c1d = fv * cd + iv * gv;
            h1d = ov * tanh_fast(c1d);
        }

        // dec2 gates: x = h = h1 -> summed (Wih2+Whh2) row
        float g2 = dot64(dw2, h1d) + db2;
        gb[r] = is_g ? tanh_fast(g2) : sigf(g2);
        __syncthreads();

        // dec2 update (redundant) + FC head on wave 0
        {
            float iv = gb[lane], fv = gb[64 + lane], gv = gb[128 + lane], ov = gb[192 + lane];
            float c2d = fv * c1d + iv * gv;
            float hh  = ov * tanh_fast(c2d);
            cd  = c2d;
            hr2 = hh;
            if (r < 64) {
                float p0 = fw0 * hh, p1 = fw1 * hh, p2 = fw2 * hh;
#pragma unroll
                for (int off = 32; off > 0; off >>= 1) {
                    p0 += __shfl_down(p0, off);
                    p1 += __shfl_down(p1, off);
                    p2 += __shfl_down(p2, off);
                }
                if (lane == 0) {
                    float* o = out + ((size_t)b * 512 + t + 1) * 3;
                    o[0] = p0 + fb0; o[1] = p1 + fb1; o[2] = p2 + fb2;
                }
            }
        }
    }
}

extern "C" void kernel_launch(void* const* d_in, const int* in_sizes, int n_in,
                              void* d_out, int out_size, void* d_ws, size_t ws_size,
                              hipStream_t stream)
{
    const float* src   = (const float*)d_in[0];
    const float* trg   = (const float*)d_in[1];
    const float* e1ih  = (const float*)d_in[2];
    const float* e1hh  = (const float*)d_in[3];
    const float* e1b   = (const float*)d_in[4];
    const float* e2ih  = (const float*)d_in[5];
    const float* e2hh  = (const float*)d_in[6];
    const float* e2b   = (const float*)d_in[7];
    const float* dd1ih = (const float*)d_in[8];
    const float* dd1hh = (const float*)d_in[9];
    const float* dd1b  = (const float*)d_in[10];
    const float* dd2ih = (const float*)d_in[11];
    const float* dd2hh = (const float*)d_in[12];
    const float* dd2b  = (const float*)d_in[13];
    const float* fcW   = (const float*)d_in[14];
    const float* fcb   = (const float*)d_in[15];
    float* out = (float*)d_out;

    // outputs[:, 0, :] stays 0; decoder fills t >= 1
    hipMemsetAsync(d_out, 0, (size_t)out_size * sizeof(float), stream);

    seq2seq_kernel<<<512, 256, 0, stream>>>(src, trg,
                                            e1ih, e1hh, e1b, e2ih, e2hh, e2b,
                                            dd1ih, dd1hh, dd1b, dd2ih, dd2hh, dd2b,
                                            fcW, fcb, out);
}

// Round 4
// 1338.231 us; speedup vs baseline: 4.1688x; 2.0018x over previous
//
#include <hip/hip_runtime.h>
#include <math.h>

typedef _Float16 f16;
typedef _Float16 f16x8 __attribute__((ext_vector_type(8)));
typedef float    f32x4 __attribute__((ext_vector_type(4)));

#define MFMA16(A, B, C) __builtin_amdgcn_mfma_f32_16x16x32_f16((A), (B), (C), 0, 0, 0)

__device__ __forceinline__ float sigf(float x) {
    return __builtin_amdgcn_rcpf(1.0f + __expf(-x));
}
__device__ __forceinline__ float tanh_fast(float x) {
    float ax = fabsf(x);
    float e  = __expf(-2.0f * ax);
    return copysignf((1.0f - e) * __builtin_amdgcn_rcpf(1.0f + e), x);
}

// Load one B-fragment (8 consecutive k of row n) from an fp32 [256x64] matrix.
// B[k][n] = W[n][k]; lane holds B[k = k0 + j][n], j=0..7.
__device__ __forceinline__ f16x8 ldfrag(const float* __restrict__ W, int n, int k0) {
    const float* p = W + (size_t)n * 64 + k0;
    f16x8 r;
#pragma unroll
    for (int j = 0; j < 8; j++) r[j] = (f16)p[j];
    return r;
}

// One block per batch element; 256 threads = 4 waves.
// Wave wv owns gate columns n = g*64 + wv*16 + (lane&15), g = i,f,g,o.
// A-fragments are broadcast (all C rows identical since M=1 real row).
__global__ __launch_bounds__(256, 2)
void seq2seq_kernel(const float* __restrict__ src, const float* __restrict__ trg,
                    const float* __restrict__ e1ih, const float* __restrict__ e1hh,
                    const float* __restrict__ e1b,
                    const float* __restrict__ e2ih, const float* __restrict__ e2hh,
                    const float* __restrict__ e2b,
                    const float* __restrict__ d1ih, const float* __restrict__ d1hh,
                    const float* __restrict__ d1b,
                    const float* __restrict__ d2ih, const float* __restrict__ d2hh,
                    const float* __restrict__ d2b,
                    const float* __restrict__ fcW, const float* __restrict__ fcb,
                    float* __restrict__ out)
{
    const int b    = blockIdx.x;
    const int tid  = threadIdx.x;
    const int wv   = tid >> 6;
    const int lane = tid & 63;
    const int quad = lane >> 4;
    const int l15  = lane & 15;
    const int u    = wv * 16 + l15;        // hidden index this lane updates

    __shared__ __align__(16) f16 xls[1024][8];   // [x0,x1,x2,0...] per src step
    __shared__ __align__(16) f16 tls[512][8];    // same for trg steps
    __shared__ __align__(16) f16 h1l[64];
    __shared__ __align__(16) f16 h2l[64];

    // ---- stage inputs as padded f16 rows (coalesced-ish, one-time) ----
    {
        const float* srow = src + (size_t)b * 3072;
        for (int t = tid; t < 1024; t += 256) {
            f16x8 v = {(f16)srow[t * 3], (f16)srow[t * 3 + 1], (f16)srow[t * 3 + 2],
                       (f16)0.f, (f16)0.f, (f16)0.f, (f16)0.f, (f16)0.f};
            *(f16x8*)xls[t] = v;
        }
        const float* trow = trg + (size_t)b * 1536;
        for (int t = tid; t < 511; t += 256) {
            f16x8 v = {(f16)trow[t * 3], (f16)trow[t * 3 + 1], (f16)trow[t * 3 + 2],
                       (f16)0.f, (f16)0.f, (f16)0.f, (f16)0.f, (f16)0.f};
            *(f16x8*)tls[t] = v;
        }
        if (tid < 64) { h1l[tid] = (f16)0.f; h2l[tid] = (f16)0.f; }
    }

    // ---- encoder B-fragments (register-resident, f16) ----
    f16x8 E1hh[4][2], E1ih[4], E2ih[4][2], E2hh[4][2];
    float B1[4], B2[4];
#pragma unroll
    for (int g = 0; g < 4; g++) {
        int n = g * 64 + u;
#pragma unroll
        for (int c = 0; c < 2; c++) {
            int k0 = c * 32 + quad * 8;
            E1hh[g][c] = ldfrag(e1hh, n, k0);
            E2ih[g][c] = ldfrag(e2ih, n, k0);
            E2hh[g][c] = ldfrag(e2hh, n, k0);
        }
        f16x8 r = {(f16)0.f, (f16)0.f, (f16)0.f, (f16)0.f,
                   (f16)0.f, (f16)0.f, (f16)0.f, (f16)0.f};
        if (quad == 0) {
            r[0] = (f16)e1ih[n * 3 + 0];
            r[1] = (f16)e1ih[n * 3 + 1];
            r[2] = (f16)e1ih[n * 3 + 2];
        }
        E1ih[g] = r;
        B1[g] = e1b[n];
        B2[g] = e2b[n];
    }

    float c1s = 0.f, c2s = 0.f;   // cell state for channel u (replicated per quad)
    __syncthreads();

    // ---------------- encoder: 1024 steps ----------------
#pragma unroll 1
    for (int t = 0; t < 1024; t++) {
        f16x8 a0 = *(const f16x8*)(h1l + quad * 8);        // h1 k 0..31
        f16x8 a1 = *(const f16x8*)(h1l + 32 + quad * 8);   // h1 k 32..63
        f16x8 b0 = *(const f16x8*)(h2l + quad * 8);        // h2 old
        f16x8 b1 = *(const f16x8*)(h2l + 32 + quad * 8);
        f16x8 ax = *(const f16x8*)(xls[t]);                // x (K=32 block, rows>=3 of B are 0)
        __syncthreads();   // B0: all old-state reads done before any write below

        f32x4 acc[4];
#pragma unroll
        for (int g = 0; g < 4; g++) {
            f32x4 a = {B1[g], B1[g], B1[g], B1[g]};
            a = MFMA16(a0, E1hh[g][0], a);
            a = MFMA16(a1, E1hh[g][1], a);
            a = MFMA16(ax, E1ih[g], a);
            acc[g] = a;
        }
        float i1 = sigf(acc[0][0]), f1 = sigf(acc[1][0]);
        float g1 = tanh_fast(acc[2][0]), o1 = sigf(acc[3][0]);
        c1s = f1 * c1s + i1 * g1;
        float h1n = o1 * tanh_fast(c1s);
        if (quad == 0) h1l[u] = (f16)h1n;
        __syncthreads();   // BA: h1 new visible

        f16x8 n0 = *(const f16x8*)(h1l + quad * 8);
        f16x8 n1 = *(const f16x8*)(h1l + 32 + quad * 8);
#pragma unroll
        for (int g = 0; g < 4; g++) {
            f32x4 a = {B2[g], B2[g], B2[g], B2[g]};
            a = MFMA16(n0, E2ih[g][0], a);
            a = MFMA16(n1, E2ih[g][1], a);
            a = MFMA16(b0, E2hh[g][0], a);
            a = MFMA16(b1, E2hh[g][1], a);
            acc[g] = a;
        }
        float i2 = sigf(acc[0][0]), f2 = sigf(acc[1][0]);
        float g2 = tanh_fast(acc[2][0]), o2 = sigf(acc[3][0]);
        c2s = f2 * c2s + i2 * g2;
        float h2n = o2 * tanh_fast(c2s);
        if (quad == 0) h2l[u] = (f16)h2n;
        __syncthreads();   // BB: h2 new visible
    }

    // ---------------- decoder B-fragments (reuse dead encoder regs) ----------
    f16x8 D1hh[4][2], D1ih[4], W2s[4][2];
    float Bd1[4], Bd2[4];
#pragma unroll
    for (int g = 0; g < 4; g++) {
        int n = g * 64 + u;
#pragma unroll
        for (int c = 0; c < 2; c++) {
            int k0 = c * 32 + quad * 8;
            D1hh[g][c] = ldfrag(d1hh, n, k0);
            const float* pa = d2ih + (size_t)n * 64 + k0;
            const float* pb = d2hh + (size_t)n * 64 + k0;
            f16x8 r;
#pragma unroll
            for (int j = 0; j < 8; j++) r[j] = (f16)(pa[j] + pb[j]);
            W2s[g][c] = r;
        }
        f16x8 r = {(f16)0.f, (f16)0.f, (f16)0.f, (f16)0.f,
                   (f16)0.f, (f16)0.f, (f16)0.f, (f16)0.f};
        if (quad == 0) {
            r[0] = (f16)d1ih[n * 3 + 0];
            r[1] = (f16)d1ih[n * 3 + 1];
            r[2] = (f16)d1ih[n * 3 + 2];
        }
        D1ih[g] = r;
        Bd1[g] = d1b[n];
        Bd2[g] = d2b[n];
    }
    float fw0 = 0.f, fw1 = 0.f, fw2 = 0.f;
    float fb0 = fcb[0], fb1 = fcb[1], fb2 = fcb[2];
    if (wv == 0) { fw0 = fcW[lane]; fw1 = fcW[64 + lane]; fw2 = fcW[128 + lane]; }

    // decoder carry: h in h2l (LDS), c in regs
    float cd = c2s;

    // ---------------- decoder: 511 steps ----------------
#pragma unroll 1
    for (int t = 0; t < 511; t++) {
        f16x8 a0 = *(const f16x8*)(h2l + quad * 8);
        f16x8 a1 = *(const f16x8*)(h2l + 32 + quad * 8);
        f16x8 ax = *(const f16x8*)(tls[t]);
        __syncthreads();   // B0

        f32x4 acc[4];
#pragma unroll
        for (int g = 0; g < 4; g++) {
            f32x4 a = {Bd1[g], Bd1[g], Bd1[g], Bd1[g]};
            a = MFMA16(a0, D1hh[g][0], a);
            a = MFMA16(a1, D1hh[g][1], a);
            a = MFMA16(ax, D1ih[g], a);
            acc[g] = a;
        }
        float i1 = sigf(acc[0][0]), f1 = sigf(acc[1][0]);
        float g1 = tanh_fast(acc[2][0]), o1 = sigf(acc[3][0]);
        float c1d = f1 * cd + i1 * g1;
        float h1d = o1 * tanh_fast(c1d);
        if (quad == 0) h1l[u] = (f16)h1d;
        __syncthreads();   // BA

        f16x8 n0 = *(const f16x8*)(h1l + quad * 8);
        f16x8 n1 = *(const f16x8*)(h1l + 32 + quad * 8);
#pragma unroll
        for (int g = 0; g < 4; g++) {
            f32x4 a = {Bd2[g], Bd2[g], Bd2[g], Bd2[g]};
            a = MFMA16(n0, W2s[g][0], a);
            a = MFMA16(n1, W2s[g][1], a);
            acc[g] = a;
        }
        float i2 = sigf(acc[0][0]), f2 = sigf(acc[1][0]);
        float g2 = tanh_fast(acc[2][0]), o2 = sigf(acc[3][0]);
        float c2d = f2 * c1d + i2 * g2;
        float h2n = o2 * tanh_fast(c2d);
        cd = c2d;
        if (quad == 0) h2l[u] = (f16)h2n;
        __syncthreads();   // BB: h2 new visible (also for FC read)

        if (wv == 0) {
            float hv = (float)h2l[lane];
            float p0 = fw0 * hv, p1 = fw1 * hv, p2 = fw2 * hv;
#pragma unroll
            for (int off = 32; off > 0; off >>= 1) {
                p0 += __shfl_down(p0, off);
                p1 += __shfl_down(p1, off);
                p2 += __shfl_down(p2, off);
            }
            if (lane == 0) {
                float* o = out + ((size_t)b * 512 + t + 1) * 3;
                o[0] = p0 + fb0; o[1] = p1 + fb1; o[2] = p2 + fb2;
            }
        }
    }
}

extern "C" void kernel_launch(void* const* d_in, const int* in_sizes, int n_in,
                              void* d_out, int out_size, void* d_ws, size_t ws_size,
                              hipStream_t stream)
{
    const float* src   = (const float*)d_in[0];
    const float* trg   = (const float*)d_in[1];
    const float* e1ih  = (const float*)d_in[2];
    const float* e1hh  = (const float*)d_in[3];
    const float* e1b   = (const float*)d_in[4];
    const float* e2ih  = (const float*)d_in[5];
    const float* e2hh  = (const float*)d_in[6];
    const float* e2b   = (const float*)d_in[7];
    const float* dd1ih = (const float*)d_in[8];
    const float* dd1hh = (const float*)d_in[9];
    const float* dd1b  = (const float*)d_in[10];
    const float* dd2ih = (const float*)d_in[11];
    const float* dd2hh = (const float*)d_in[12];
    const float* dd2b  = (const float*)d_in[13];
    const float* fcW   = (const float*)d_in[14];
    const float* fcb   = (const float*)d_in[15];
    float* out = (float*)d_out;

    // outputs[:, 0, :] stays 0; decoder fills t >= 1
    hipMemsetAsync(d_out, 0, (size_t)out_size * sizeof(float), stream);

    seq2seq_kernel<<<512, 256, 0, stream>>>(src, trg,
                                            e1ih, e1hh, e1b, e2ih, e2hh, e2b,
                                            dd1ih, dd1hh, dd1b, dd2ih, dd2hh, dd2b,
                                            fcW, fcb, out);
}